// Round 12
// baseline (61.579 us; speedup 1.0000x reference)
//
#include <hip/hip_runtime.h>
#include <cstdint>
#include <cstddef>
#include <math.h>

#define B 16
#define S 200
#define D 128
#define VOCAB 100000
#define V4 (VOCAB / 4)                 // 25000 float4 columns
#define SCH 8
#define VTILE 256                      // vocab words per block
#define NBLK ((VOCAB + VTILE - 1) / VTILE)   // 391
#define CH 16                          // d-rows per chunk
#define NCH (2 * D / CH)               // 16 chunks

// K1: attention scores: per block = one (b, chunk of 8 s). 128 threads (one per e-dim).
__global__ __launch_bounds__(128) void k_scores(
    const float* __restrict__ x,
    const float* __restrict__ Wq, const float* __restrict__ bq,
    const float* __restrict__ Wk, const float* __restrict__ bk,
    const float* __restrict__ Wv, const float* __restrict__ bv,
    float* __restrict__ scores)
{
  const int b  = blockIdx.x / (S / SCH);
  const int s0 = (blockIdx.x % (S / SCH)) * SCH;
  const int e  = threadIdx.x;

  __shared__ float lx[SCH][D];
  __shared__ float l0[D];
  __shared__ float sred[2][SCH];

  l0[e] = x[(size_t)b * S * D + e];
  #pragma unroll
  for (int i = 0; i < SCH; i++) lx[i][e] = x[((size_t)b * S + s0 + i) * D + e];
  __syncthreads();

  float q[SCH];
  const float bqe = bq[e];
  #pragma unroll
  for (int i = 0; i < SCH; i++) q[i] = bqe;
  float kk = bk[e];

  for (int d = 0; d < D; d++) {
    const float wq = Wq[d * D + e];
    const float wk = Wk[d * D + e];
    const float x0 = l0[d];
    kk += x0 * wk;
    #pragma unroll
    for (int i = 0; i < SCH; i++) q[i] += lx[i][d] * wq;
  }

  const float wv  = Wv[e];
  const float bv0 = bv[0];
  #pragma unroll
  for (int i = 0; i < SCH; i++) {
    float val = tanhf(q[i] + kk) * wv;
    #pragma unroll
    for (int off = 32; off > 0; off >>= 1) val += __shfl_down(val, off, 64);
    if ((e & 63) == 0) sred[e >> 6][i] = val;
  }
  __syncthreads();
  if (e < SCH) scores[b * S + s0 + e] = sred[0][e] + sred[1][e] + bv0;
}

// K2: softmax over S + c_s; 512 threads: 4 s-splits x 128 d.
// Writes cvec[dd*16 + b], dd 0..255 (h_t | c_s).
__global__ __launch_bounds__(512) void k_csum(
    const float* __restrict__ x, const float* __restrict__ scores,
    float* __restrict__ cvec)
{
  const int b = blockIdx.x;
  const int t = threadIdx.x;
  __shared__ float pr[S];
  __shared__ float redm[9];
  __shared__ float reds[9];
  __shared__ float cpart[3][D];

  float v = (t < S) ? scores[b * S + t] : -INFINITY;
  float m = v;
  #pragma unroll
  for (int off = 32; off > 0; off >>= 1) m = fmaxf(m, __shfl_down(m, off, 64));
  if ((t & 63) == 0) redm[t >> 6] = m;
  __syncthreads();
  if (t == 0) {
    float mm = redm[0];
    #pragma unroll
    for (int i = 1; i < 8; i++) mm = fmaxf(mm, redm[i]);
    redm[8] = mm;
  }
  __syncthreads();
  const float mx = redm[8];

  float e = (t < S) ? expf(v - mx) : 0.f;
  float s = e;
  #pragma unroll
  for (int off = 32; off > 0; off >>= 1) s += __shfl_down(s, off, 64);
  if ((t & 63) == 0) reds[t >> 6] = s;
  __syncthreads();
  if (t == 0) {
    float ss = 0.f;
    #pragma unroll
    for (int i = 0; i < 8; i++) ss += reds[i];
    reds[8] = ss;
  }
  __syncthreads();
  const float inv = 1.0f / reds[8];
  if (t < S) pr[t] = e * inv;
  __syncthreads();

  const int d = t & 127;
  const int sq = t >> 7;
  float acc = 0.f;
  const float* xb = x + ((size_t)b * S + sq * 50) * D + d;
  #pragma unroll 5
  for (int s2 = 0; s2 < 50; s2++) acc += pr[sq * 50 + s2] * xb[s2 * D];
  if (sq) cpart[sq - 1][d] = acc;
  __syncthreads();
  if (sq == 0) {
    cvec[d * B + b]       = x[(size_t)b * S * D + d];
    cvec[(D + d) * B + b] = acc + cpart[0][d] + cpart[1][d] + cpart[2][d];
  }
}

// K3: fused gemv + bias + mask + exp + per-block partial sums.
// R11 structure, but c is NOT staged in LDS: it is read straight from global
// with wave-uniform indices (dq is readfirstlane'd; c/r/bb are unrolled
// constants) so the compiler scalarizes to s_load via the scalar cache
// (lgkmcnt; no LDS-pipe, no vmcnt pollution). R11's hidden cost was 16
// broadcast ds_read_b128 per thread-chunk for c = ~11-16 us/CU of LDS issue.
// DS traffic per chunk drops 20 -> 4 b128 (the W reads only).
__global__ __launch_bounds__(256, 2) void k_gemv(
    const float* __restrict__ cvec, const float* __restrict__ Wec,
    const float* __restrict__ bec, const int* __restrict__ ids,
    float* __restrict__ out, float* __restrict__ partial)
{
  __shared__ __align__(16) char arena[36864];      // 32 KB wbuf; reused for RED (34816 B)
  float (*wbuf)[CH][VTILE] = (float (*)[CH][VTILE])arena;   // [2][16][256]
  __shared__ unsigned mbit[B * 8];                 // 16 b x 256 v bits

  const int t    = threadIdx.x;
  const int lane = t & 63;
  const int dq   = __builtin_amdgcn_readfirstlane(t >> 6);  // wave id

  if (t < B * 8) mbit[t] = 0u;

  const int vbase = blockIdx.x * VTILE;
  const int v4    = blockIdx.x * 64 + lane;    // this thread's float4 column
  const bool valid = (v4 < V4);
  const int v4c   = valid ? v4 : (V4 - 1);
  // per-lane source offset within a d-row (clamped for the tail block)
  const int laneoff = (vbase + lane * 4 + 3 < VOCAB) ? lane * 4 : 0;

#define STAGE(bufi, c)                                                      \
  { _Pragma("unroll")                                                       \
    for (int r = 0; r < 4; r++) {                                           \
      const int d = (c) * CH + dq * 4 + r;                                  \
      const float* gp = Wec + (size_t)d * VOCAB + vbase + laneoff;          \
      float* lp = &wbuf[bufi][dq * 4 + r][0];                               \
      __builtin_amdgcn_global_load_lds(                                     \
          (const __attribute__((address_space(1))) void*)gp,                \
          (__attribute__((address_space(3))) void*)lp, 16, 0, 0);           \
    } }

  float4 acc[16];
  #pragma unroll
  for (int i = 0; i < 16; i++) acc[i] = make_float4(0.f, 0.f, 0.f, 0.f);

  STAGE(0, 0)

  // build mask bitmap for this block's v-range (overlaps with chunk-0 DMA)
  for (int i = t; i < B * S; i += 256) {
    const int id = ids[i];
    if (id > 1 && id >= vbase && id < vbase + VTILE) {
      const int lv = id - vbase;
      atomicOr(&mbit[(i / S) * 8 + (lv >> 5)], 1u << (lv & 31));
    }
  }

  __syncthreads();      // covers bitmap (lgkm) + chunk 0 DMA (vmcnt)

  int cur = 0;
  for (int c = 0; c < NCH; c++) {
    if (c < NCH - 1) STAGE(cur ^ 1, c + 1)
    #pragma unroll
    for (int r = 0; r < 4; r++) {
      const float4 w = ((const float4*)&wbuf[cur][dq * 4 + r][0])[lane];
      // wave-uniform global reads -> scalar cache (s_load), no LDS traffic
      const float* cj = cvec + (c * CH + dq * 4 + r) * 16;
      #pragma unroll
      for (int bb = 0; bb < 16; bb++) {
        const float cc = cj[bb];
        acc[bb].x = fmaf(w.x, cc, acc[bb].x);
        acc[bb].y = fmaf(w.y, cc, acc[bb].y);
        acc[bb].z = fmaf(w.z, cc, acc[bb].z);
        acc[bb].w = fmaf(w.w, cc, acc[bb].w);
      }
    }
    __syncthreads();    // drains next-chunk DMA + protects buffer reuse
    cur ^= 1;
  }
#undef STAGE

  // combine the 4 waves' partial sums via LDS (reuses arena, 34816 B fits)
  float2* redp = (float2*)arena;
#define RED(q, l, b) redp[(((q) * 64 + (l)) * 17) + (b)]
#define MASKED(bb, lv) ((mbit[(bb) * 8 + ((lv) >> 5)] >> ((lv) & 31)) & 1u)

  const float4 be4 = ((const float4*)bec)[v4c];
  const int lv0 = lane * 4;
  float psum[4] = {0.f, 0.f, 0.f, 0.f};

  // Pass A: v-offsets 0,1 (acc .xy)
  #pragma unroll
  for (int bb = 0; bb < 16; bb++)
    RED(dq, lane, bb) = make_float2(acc[bb].x, acc[bb].y);
  __syncthreads();
  #pragma unroll
  for (int i = 0; i < 4; i++) {
    const int bb = dq * 4 + i;
    const float2 r0 = RED(0, lane, bb), r1 = RED(1, lane, bb);
    const float2 r2 = RED(2, lane, bb), r3 = RED(3, lane, bb);
    const float sx = r0.x + r1.x + r2.x + r3.x;
    const float sy = r0.y + r1.y + r2.y + r3.y;
    float e0 = 0.f, e1 = 0.f;
    if (valid) {
      e0 = MASKED(bb, lv0 + 0) ? 0.f : __expf(sx + be4.x);
      e1 = MASKED(bb, lv0 + 1) ? 0.f : __expf(sy + be4.y);
      *(float2*)&out[(size_t)bb * VOCAB + (size_t)v4 * 4] = make_float2(e0, e1);
    }
    psum[i] += e0 + e1;
  }
  __syncthreads();

  // Pass B: v-offsets 2,3 (acc .zw)
  #pragma unroll
  for (int bb = 0; bb < 16; bb++)
    RED(dq, lane, bb) = make_float2(acc[bb].z, acc[bb].w);
  __syncthreads();
  #pragma unroll
  for (int i = 0; i < 4; i++) {
    const int bb = dq * 4 + i;
    const float2 r0 = RED(0, lane, bb), r1 = RED(1, lane, bb);
    const float2 r2 = RED(2, lane, bb), r3 = RED(3, lane, bb);
    const float sz = r0.x + r1.x + r2.x + r3.x;
    const float sw = r0.y + r1.y + r2.y + r3.y;
    float e2 = 0.f, e3 = 0.f;
    if (valid) {
      e2 = MASKED(bb, lv0 + 2) ? 0.f : __expf(sz + be4.z);
      e3 = MASKED(bb, lv0 + 3) ? 0.f : __expf(sw + be4.w);
      *(float2*)&out[(size_t)bb * VOCAB + (size_t)v4 * 4 + 2] = make_float2(e2, e3);
    }
    psum[i] += e2 + e3;
  }
#undef RED
#undef MASKED

  #pragma unroll
  for (int i = 0; i < 4; i++) {
    float s = psum[i];
    #pragma unroll
    for (int off = 32; off > 0; off >>= 1) s += __shfl_down(s, off, 64);
    if (lane == 0) partial[blockIdx.x * 16 + dq * 4 + i] = s;
  }
}

// K4: normalize; each block reduces the 391 partials for its batch inline
// (1.6 KB redundant read per block, fully parallel), then scales float4.
__global__ __launch_bounds__(256) void k_norm(float* __restrict__ out,
                                              const float* __restrict__ partial)
{
  const int b  = blockIdx.y;
  const int t  = threadIdx.x;
  __shared__ float red[4];

  float s = 0.f;
  for (int j = t; j < NBLK; j += 256) s += partial[j * 16 + b];
  #pragma unroll
  for (int off = 32; off > 0; off >>= 1) s += __shfl_down(s, off, 64);
  if ((t & 63) == 0) red[t >> 6] = s;
  __syncthreads();
  const float iv = 1.0f / (red[0] + red[1] + red[2] + red[3]);

  const int i4 = blockIdx.x * 256 + t;
  if (i4 < V4) {
    float4* p = (float4*)out + (size_t)b * V4 + i4;
    float4 q = *p;
    q.x *= iv; q.y *= iv; q.z *= iv; q.w *= iv;
    *p = q;
  }
}

extern "C" void kernel_launch(void* const* d_in, const int* in_sizes, int n_in,
                              void* d_out, int out_size, void* d_ws, size_t ws_size,
                              hipStream_t stream)
{
  const float* x   = (const float*)d_in[0];
  const int*   ids = (const int*)d_in[1];
  const float* Wq  = (const float*)d_in[2];
  const float* bq  = (const float*)d_in[3];
  const float* Wk  = (const float*)d_in[4];
  const float* bk  = (const float*)d_in[5];
  const float* Wv  = (const float*)d_in[6];
  const float* bv  = (const float*)d_in[7];
  const float* Wec = (const float*)d_in[8];
  const float* bec = (const float*)d_in[9];
  float* out = (float*)d_out;
  float* ws  = (float*)d_ws;

  float* scores  = ws;            // 3200
  float* cvec    = ws + 3200;     // 4096  ([256][16])
  float* partial = ws + 7296;     // NBLK*16 = 6256

  k_scores <<<dim3(B * (S / SCH)), dim3(128), 0, stream>>>(x, Wq, bq, Wk, bk, Wv, bv, scores);
  k_csum   <<<dim3(B),             dim3(512), 0, stream>>>(x, scores, cvec);
  k_gemv   <<<dim3(NBLK),          dim3(256), 0, stream>>>(cvec, Wec, bec, ids, out, partial);
  k_norm   <<<dim3((V4 + 255) / 256, B), dim3(256), 0, stream>>>(out, partial);
}

// Round 13
// 56.208 us; speedup vs baseline: 1.0955x; 1.0955x over previous
//
#include <hip/hip_runtime.h>
#include <cstdint>
#include <cstddef>
#include <math.h>

#define B 16
#define S 200
#define D 128
#define VOCAB 100000
#define V4 (VOCAB / 4)                 // 25000 float4 columns
#define SCH 8
#define VTILE 256                      // vocab words per block
#define NBLK ((VOCAB + VTILE - 1) / VTILE)   // 391
#define CH 16                          // d-rows per chunk
#define NCH (2 * D / CH)               // 16 chunks

// K1: attention scores: per block = one (b, chunk of 8 s). 128 threads (one per e-dim).
__global__ __launch_bounds__(128) void k_scores(
    const float* __restrict__ x,
    const float* __restrict__ Wq, const float* __restrict__ bq,
    const float* __restrict__ Wk, const float* __restrict__ bk,
    const float* __restrict__ Wv, const float* __restrict__ bv,
    float* __restrict__ scores)
{
  const int b  = blockIdx.x / (S / SCH);
  const int s0 = (blockIdx.x % (S / SCH)) * SCH;
  const int e  = threadIdx.x;

  __shared__ float lx[SCH][D];
  __shared__ float l0[D];
  __shared__ float sred[2][SCH];

  l0[e] = x[(size_t)b * S * D + e];
  #pragma unroll
  for (int i = 0; i < SCH; i++) lx[i][e] = x[((size_t)b * S + s0 + i) * D + e];
  __syncthreads();

  float q[SCH];
  const float bqe = bq[e];
  #pragma unroll
  for (int i = 0; i < SCH; i++) q[i] = bqe;
  float kk = bk[e];

  for (int d = 0; d < D; d++) {
    const float wq = Wq[d * D + e];
    const float wk = Wk[d * D + e];
    const float x0 = l0[d];
    kk += x0 * wk;
    #pragma unroll
    for (int i = 0; i < SCH; i++) q[i] += lx[i][d] * wq;
  }

  const float wv  = Wv[e];
  const float bv0 = bv[0];
  #pragma unroll
  for (int i = 0; i < SCH; i++) {
    float val = tanhf(q[i] + kk) * wv;
    #pragma unroll
    for (int off = 32; off > 0; off >>= 1) val += __shfl_down(val, off, 64);
    if ((e & 63) == 0) sred[e >> 6][i] = val;
  }
  __syncthreads();
  if (e < SCH) scores[b * S + s0 + e] = sred[0][e] + sred[1][e] + bv0;
}

// K2: softmax over S + c_s; 512 threads: 4 s-splits x 128 d.
// Writes cvec[dd*16 + b], dd 0..255 (h_t | c_s).
__global__ __launch_bounds__(512) void k_csum(
    const float* __restrict__ x, const float* __restrict__ scores,
    float* __restrict__ cvec)
{
  const int b = blockIdx.x;
  const int t = threadIdx.x;
  __shared__ float pr[S];
  __shared__ float redm[9];
  __shared__ float reds[9];
  __shared__ float cpart[3][D];

  float v = (t < S) ? scores[b * S + t] : -INFINITY;
  float m = v;
  #pragma unroll
  for (int off = 32; off > 0; off >>= 1) m = fmaxf(m, __shfl_down(m, off, 64));
  if ((t & 63) == 0) redm[t >> 6] = m;
  __syncthreads();
  if (t == 0) {
    float mm = redm[0];
    #pragma unroll
    for (int i = 1; i < 8; i++) mm = fmaxf(mm, redm[i]);
    redm[8] = mm;
  }
  __syncthreads();
  const float mx = redm[8];

  float e = (t < S) ? expf(v - mx) : 0.f;
  float s = e;
  #pragma unroll
  for (int off = 32; off > 0; off >>= 1) s += __shfl_down(s, off, 64);
  if ((t & 63) == 0) reds[t >> 6] = s;
  __syncthreads();
  if (t == 0) {
    float ss = 0.f;
    #pragma unroll
    for (int i = 0; i < 8; i++) ss += reds[i];
    reds[8] = ss;
  }
  __syncthreads();
  const float inv = 1.0f / reds[8];
  if (t < S) pr[t] = e * inv;
  __syncthreads();

  const int d = t & 127;
  const int sq = t >> 7;
  float acc = 0.f;
  const float* xb = x + ((size_t)b * S + sq * 50) * D + d;
  #pragma unroll 5
  for (int s2 = 0; s2 < 50; s2++) acc += pr[sq * 50 + s2] * xb[s2 * D];
  if (sq) cpart[sq - 1][d] = acc;
  __syncthreads();
  if (sq == 0) {
    cvec[d * B + b]       = x[(size_t)b * S * D + d];
    cvec[(D + d) * B + b] = acc + cpart[0][d] + cpart[1][d] + cpart[2][d];
  }
}

// K3: fused gemv + bias + mask + exp + per-block partial sums.
// KEY CHANGE vs R11/R12: wave-PRIVATE LDS rows (wave dq stages and reads only
// rows dq*4+r) -> the inner-loop __syncthreads was protecting nothing, and its
// implicit vmcnt(0) drain was serializing the DMA to 1 chunk in flight
// (~2500 cy/chunk = the invariant ~40us). Now: NO inner barrier, 3 rotating
// buffers, DMA issued 2 chunks ahead, counted s_waitcnt vmcnt(8) per chunk
// (loads stay in flight across chunk boundaries -- T4). ds_read consumers are
// memory ops, ordered by the asm "memory" clobber; sched_barrier(0) pins each
// chunk boundary (rule #18 safety).
__global__ __launch_bounds__(256, 2) void k_gemv(
    const float* __restrict__ cvec, const float* __restrict__ Wec,
    const float* __restrict__ bec, const int* __restrict__ ids,
    float* __restrict__ out, float* __restrict__ partial)
{
  __shared__ __align__(16) char arena[49152];      // [3][16][256] wbuf; RED reuse
  float (*wbuf)[CH][VTILE] = (float (*)[CH][VTILE])arena;
  __shared__ __align__(16) float cl[4096];         // [256 d][16 b] staged c
  __shared__ unsigned mbit[B * 8];                 // 16 b x 256 v bits

  const int t    = threadIdx.x;
  const int lane = t & 63;
  const int dq   = __builtin_amdgcn_readfirstlane(t >> 6);  // wave id

  if (t < B * 8) mbit[t] = 0u;

  const int vbase = blockIdx.x * VTILE;
  const int v4    = blockIdx.x * 64 + lane;    // this thread's float4 column
  const bool valid = (v4 < V4);
  const int v4c   = valid ? v4 : (V4 - 1);
  // per-lane source offset within a d-row (clamped for the tail block)
  const int laneoff = (vbase + lane * 4 + 3 < VOCAB) ? lane * 4 : 0;

#define STAGE(bufi, c)                                                      \
  { _Pragma("unroll")                                                       \
    for (int r = 0; r < 4; r++) {                                           \
      const int d = (c) * CH + dq * 4 + r;                                  \
      const float* gp = Wec + (size_t)d * VOCAB + vbase + laneoff;          \
      float* lp = &wbuf[bufi][dq * 4 + r][0];                               \
      __builtin_amdgcn_global_load_lds(                                     \
          (const __attribute__((address_space(1))) void*)gp,                \
          (__attribute__((address_space(3))) void*)lp, 16, 0, 0);           \
    } }

#define COMP(bufi, c)                                                      \
  { _Pragma("unroll")                                                      \
    for (int r = 0; r < 4; r++) {                                          \
      const float4 w = ((const float4*)&wbuf[bufi][dq * 4 + r][0])[lane];  \
      const float* cj = cl + ((c) * CH + dq * 4 + r) * 16;                 \
      _Pragma("unroll")                                                    \
      for (int bb = 0; bb < 16; bb++) {                                    \
        const float cc = cj[bb];                                           \
        acc[bb].x = fmaf(w.x, cc, acc[bb].x);                              \
        acc[bb].y = fmaf(w.y, cc, acc[bb].y);                              \
        acc[bb].z = fmaf(w.z, cc, acc[bb].z);                              \
        acc[bb].w = fmaf(w.w, cc, acc[bb].w);                              \
      } } }

  float4 acc[16];
  #pragma unroll
  for (int i = 0; i < 16; i++) acc[i] = make_float4(0.f, 0.f, 0.f, 0.f);

  // stage c once (coalesced float4)
  {
    const float4* src = (const float4*)cvec;
    float4* dst = (float4*)cl;
    #pragma unroll
    for (int i = 0; i < 4; i++) dst[t + 256 * i] = src[t + 256 * i];
  }

  STAGE(0, 0)
  STAGE(1, 1)

  // build mask bitmap for this block's v-range (overlaps with chunk 0/1 DMA)
  for (int i = t; i < B * S; i += 256) {
    const int id = ids[i];
    if (id > 1 && id >= vbase && id < vbase + VTILE) {
      const int lv = id - vbase;
      atomicOr(&mbit[(i / S) * 8 + (lv >> 5)], 1u << (lv & 31));
    }
  }

  __syncthreads();      // cl + mbit visible to all; drains chunk 0/1 DMA too

  // barrier-free pipelined main loop: issue chunk c+2, wait for chunk c
  // (vmcnt(8) leaves chunks c+1, c+2 in flight), compute chunk c.
  for (int c = 0; c < NCH - 2; c++) {
    STAGE((c + 2) % 3, c + 2)
    asm volatile("s_waitcnt vmcnt(8)" ::: "memory");
    __builtin_amdgcn_sched_barrier(0);
    COMP(c % 3, c)
    __builtin_amdgcn_sched_barrier(0);
  }
  asm volatile("s_waitcnt vmcnt(4)" ::: "memory");
  __builtin_amdgcn_sched_barrier(0);
  COMP((NCH - 2) % 3, NCH - 2)
  asm volatile("s_waitcnt vmcnt(0)" ::: "memory");
  __builtin_amdgcn_sched_barrier(0);
  COMP((NCH - 1) % 3, NCH - 1)

#undef STAGE
#undef COMP

  __syncthreads();      // all waves done reading wbuf; safe to reuse as RED

  // combine the 4 waves' partial sums via LDS (reuses arena, 34816 B fits)
  float2* redp = (float2*)arena;
#define RED(q, l, b) redp[(((q) * 64 + (l)) * 17) + (b)]
#define MASKED(bb, lv) ((mbit[(bb) * 8 + ((lv) >> 5)] >> ((lv) & 31)) & 1u)

  const float4 be4 = ((const float4*)bec)[v4c];
  const int lv0 = lane * 4;
  float psum[4] = {0.f, 0.f, 0.f, 0.f};

  // Pass A: v-offsets 0,1 (acc .xy)
  #pragma unroll
  for (int bb = 0; bb < 16; bb++)
    RED(dq, lane, bb) = make_float2(acc[bb].x, acc[bb].y);
  __syncthreads();
  #pragma unroll
  for (int i = 0; i < 4; i++) {
    const int bb = dq * 4 + i;
    const float2 r0 = RED(0, lane, bb), r1 = RED(1, lane, bb);
    const float2 r2 = RED(2, lane, bb), r3 = RED(3, lane, bb);
    const float sx = r0.x + r1.x + r2.x + r3.x;
    const float sy = r0.y + r1.y + r2.y + r3.y;
    float e0 = 0.f, e1 = 0.f;
    if (valid) {
      e0 = MASKED(bb, lv0 + 0) ? 0.f : __expf(sx + be4.x);
      e1 = MASKED(bb, lv0 + 1) ? 0.f : __expf(sy + be4.y);
      *(float2*)&out[(size_t)bb * VOCAB + (size_t)v4 * 4] = make_float2(e0, e1);
    }
    psum[i] += e0 + e1;
  }
  __syncthreads();

  // Pass B: v-offsets 2,3 (acc .zw)
  #pragma unroll
  for (int bb = 0; bb < 16; bb++)
    RED(dq, lane, bb) = make_float2(acc[bb].z, acc[bb].w);
  __syncthreads();
  #pragma unroll
  for (int i = 0; i < 4; i++) {
    const int bb = dq * 4 + i;
    const float2 r0 = RED(0, lane, bb), r1 = RED(1, lane, bb);
    const float2 r2 = RED(2, lane, bb), r3 = RED(3, lane, bb);
    const float sz = r0.x + r1.x + r2.x + r3.x;
    const float sw = r0.y + r1.y + r2.y + r3.y;
    float e2 = 0.f, e3 = 0.f;
    if (valid) {
      e2 = MASKED(bb, lv0 + 2) ? 0.f : __expf(sz + be4.z);
      e3 = MASKED(bb, lv0 + 3) ? 0.f : __expf(sw + be4.w);
      *(float2*)&out[(size_t)bb * VOCAB + (size_t)v4 * 4 + 2] = make_float2(e2, e3);
    }
    psum[i] += e2 + e3;
  }
#undef RED
#undef MASKED

  #pragma unroll
  for (int i = 0; i < 4; i++) {
    float s = psum[i];
    #pragma unroll
    for (int off = 32; off > 0; off >>= 1) s += __shfl_down(s, off, 64);
    if (lane == 0) partial[blockIdx.x * 16 + dq * 4 + i] = s;
  }
}

// K4: normalize; each block reduces the 391 partials for its batch inline
// (1.6 KB redundant read per block, fully parallel), then scales float4.
__global__ __launch_bounds__(256) void k_norm(float* __restrict__ out,
                                              const float* __restrict__ partial)
{
  const int b  = blockIdx.y;
  const int t  = threadIdx.x;
  __shared__ float red[4];

  float s = 0.f;
  for (int j = t; j < NBLK; j += 256) s += partial[j * 16 + b];
  #pragma unroll
  for (int off = 32; off > 0; off >>= 1) s += __shfl_down(s, off, 64);
  if ((t & 63) == 0) red[t >> 6] = s;
  __syncthreads();
  const float iv = 1.0f / (red[0] + red[1] + red[2] + red[3]);

  const int i4 = blockIdx.x * 256 + t;
  if (i4 < V4) {
    float4* p = (float4*)out + (size_t)b * V4 + i4;
    float4 q = *p;
    q.x *= iv; q.y *= iv; q.z *= iv; q.w *= iv;
    *p = q;
  }
}

extern "C" void kernel_launch(void* const* d_in, const int* in_sizes, int n_in,
                              void* d_out, int out_size, void* d_ws, size_t ws_size,
                              hipStream_t stream)
{
  const float* x   = (const float*)d_in[0];
  const int*   ids = (const int*)d_in[1];
  const float* Wq  = (const float*)d_in[2];
  const float* bq  = (const float*)d_in[3];
  const float* Wk  = (const float*)d_in[4];
  const float* bk  = (const float*)d_in[5];
  const float* Wv  = (const float*)d_in[6];
  const float* bv  = (const float*)d_in[7];
  const float* Wec = (const float*)d_in[8];
  const float* bec = (const float*)d_in[9];
  float* out = (float*)d_out;
  float* ws  = (float*)d_ws;

  float* scores  = ws;            // 3200
  float* cvec    = ws + 3200;     // 4096  ([256][16])
  float* partial = ws + 7296;     // NBLK*16 = 6256

  k_scores <<<dim3(B * (S / SCH)), dim3(128), 0, stream>>>(x, Wq, bq, Wk, bk, Wv, bv, scores);
  k_csum   <<<dim3(B),             dim3(512), 0, stream>>>(x, scores, cvec);
  k_gemv   <<<dim3(NBLK),          dim3(256), 0, stream>>>(cvec, Wec, bec, ids, out, partial);
  k_norm   <<<dim3((V4 + 255) / 256, B), dim3(256), 0, stream>>>(out, partial);
}